// Round 5
// baseline (67.870 us; speedup 1.0000x reference)
//
#include <hip/hip_runtime.h>

#define NB 4
#define SEQ 2048
#define EMB 32
#define HEADS 8
#define HD 4

typedef float v2f __attribute__((ext_vector_type(2)));
typedef unsigned int uint;

__device__ __forceinline__ v2f splat2(float x) { v2f r; r.x = x; r.y = x; return r; }
__device__ __forceinline__ v2f pkfma(v2f a, v2f b, v2f c) {
  return __builtin_elementwise_fma(a, b, c);
}

// Pack mask (N,1,Q,K) int32 -> 1 bit per key. Word w of row r covers keys
// [32w..32w+31]; bit b = (mask != 0). Each thread reads one int4 (4 keys),
// 8-lane groups OR-combine into one uint32.
__global__ __launch_bounds__(256) void mask_pack_kernel(
    const int* __restrict__ mask, uint* __restrict__ pmw) {
  int g = blockIdx.x * 256 + threadIdx.x;       // int4 index
  const int4 v = ((const int4*)mask)[g];
  uint nib = (uint)(v.x != 0) | ((uint)(v.y != 0) << 1) |
             ((uint)(v.z != 0) << 2) | ((uint)(v.w != 0) << 3);
  int lane = threadIdx.x & 63;
  uint w = nib << (4 * (lane & 7));
  w |= __shfl_xor(w, 1);
  w |= __shfl_xor(w, 2);
  w |= __shfl_xor(w, 4);
  if ((lane & 7) == 0) pmw[g >> 3] = w;
}

// K and V projections in one launch. First half of grid does K, second half V.
__global__ __launch_bounds__(256) void proj_kv_kernel(
    const float* __restrict__ key, const float* __restrict__ value,
    const float* __restrict__ Wk, const float* __restrict__ bk,
    const float* __restrict__ Wv, const float* __restrict__ bv,
    float* __restrict__ Kp, float* __restrict__ Vp) {
  const int half = NB * SEQ / 8;
  bool isV = blockIdx.x >= half;
  const float* X = isV ? value : key;
  const float* W = isV ? Wv : Wk;
  const float* b = isV ? bv : bk;
  float* P = isV ? Vp : Kp;
  int blk = isV ? (blockIdx.x - half) : blockIdx.x;

  __shared__ float sW[EMB][EMB];
  __shared__ float sb[EMB];
  __shared__ float sX[8][EMB];
  int t = threadIdx.x;
  for (int i = t; i < EMB * EMB; i += 256) sW[i >> 5][i & 31] = W[i];
  if (t < EMB) sb[t] = b[t];
  size_t row0 = (size_t)blk * 8;
  int r = t >> 5, c = t & 31;
  sX[r][c] = X[(row0 + r) * EMB + c];
  __syncthreads();
  float acc = sb[c];
#pragma unroll
  for (int d = 0; d < EMB; ++d) acc = fmaf(sX[r][d], sW[d][c], acc);
  P[(row0 + r) * EMB + c] = acc;
}

__device__ __forceinline__ void load_tile(
    const float*& kptr, const float*& vptr, const uint*& mwp,
    float4 (&KK)[4], float4 (&VV)[4], uint4& MW) {
  KK[0] = *(const float4*)(kptr);
  KK[1] = *(const float4*)(kptr + EMB);
  KK[2] = *(const float4*)(kptr + 2 * EMB);
  KK[3] = *(const float4*)(kptr + 3 * EMB);
  VV[0] = *(const float4*)(vptr);
  VV[1] = *(const float4*)(vptr + EMB);
  VV[2] = *(const float4*)(vptr + 2 * EMB);
  VV[3] = *(const float4*)(vptr + 3 * EMB);
  MW.x = mwp[0];
  MW.y = mwp[64];
  MW.z = mwp[128];
  MW.w = mwp[192];
  kptr += 32 * EMB; vptr += 32 * EMB; mwp += 1;
}

// No-max softmax: p = exp2(s), masked -> 0 (fast-path skips mask ALU when the
// tile's 4 row-words are all ones). Row-pairs packed as v2f -> v_pk_fma_f32.
__device__ __forceinline__ void compute_tile(
    const float4 (&KK)[4], const float4 (&VV)[4], const uint4& MW, int ks4,
    const v2f (&q2)[2][4], v2f (&l2)[2], v2f (&ac2)[2][4]) {
  v2f pf[2][4];
#pragma unroll
  for (int p = 0; p < 2; ++p) {
#pragma unroll
    for (int j = 0; j < 4; ++j) {
      const float4 kk = KK[j];
      v2f s = pkfma(q2[p][0], splat2(kk.x),
              pkfma(q2[p][1], splat2(kk.y),
              pkfma(q2[p][2], splat2(kk.z), q2[p][3] * splat2(kk.w))));
      pf[p][j].x = __builtin_amdgcn_exp2f(s.x);
      pf[p][j].y = __builtin_amdgcn_exp2f(s.y);
    }
  }
  uint allm = MW.x & MW.y & MW.z & MW.w;
  if (allm != 0xFFFFFFFFu) {   // wave-uniform in practice
#pragma unroll
    for (int j = 0; j < 4; ++j) {
      if (!((MW.x >> (ks4 + j)) & 1u)) pf[0][j].x = 0.0f;
      if (!((MW.y >> (ks4 + j)) & 1u)) pf[0][j].y = 0.0f;
      if (!((MW.z >> (ks4 + j)) & 1u)) pf[1][j].x = 0.0f;
      if (!((MW.w >> (ks4 + j)) & 1u)) pf[1][j].y = 0.0f;
    }
  }
#pragma unroll
  for (int p = 0; p < 2; ++p) {
    l2[p] += (pf[p][0] + pf[p][1]) + (pf[p][2] + pf[p][3]);
#pragma unroll
    for (int j = 0; j < 4; ++j) {
      const float4 vv = VV[j];
      ac2[p][0] = pkfma(pf[p][j], splat2(vv.x), ac2[p][0]);
      ac2[p][1] = pkfma(pf[p][j], splat2(vv.y), ac2[p][1]);
      ac2[p][2] = pkfma(pf[p][j], splat2(vv.z), ac2[p][2]);
      ac2[p][3] = pkfma(pf[p][j], splat2(vv.w), ac2[p][3]);
    }
  }
}

// Fused q-projection + flash attention (no-max) + out projection.
// Block = 256 threads = 4 waves; wave rl handles q-rows qrow0+4*rl..+3.
// Lane: head h = lane&7, k-split ks = lane>>3; 4 keys/thread/tile, 64 tiles.
// Register double-buffer: prefetch tile i+1 while computing tile i.
__global__ __launch_bounds__(256, 2) void attn_kernel(
    const float* __restrict__ query, const uint* __restrict__ pmw,
    const float* __restrict__ Kp, const float* __restrict__ Vp,
    const float* __restrict__ Wq, const float* __restrict__ bq,
    const float* __restrict__ Wo, const float* __restrict__ bo,
    float* __restrict__ out) {
  __shared__ float sWq[EMB][EMB];
  __shared__ float sWo[EMB][EMB];
  __shared__ float sbq[EMB];
  __shared__ float sbo[EMB];
  __shared__ float sX[16][EMB];
  __shared__ float sCtx[16][EMB + 1];

  int t = threadIdx.x;
  int n = blockIdx.x >> 7;
  int qt = blockIdx.x & 127;
  int qrow0 = qt * 16;

  int rl = t >> 6;
  int lane = t & 63;
  int h = lane & 7;
  int ks = lane >> 3;
  int ks4 = 4 * ks;

  for (int i = t; i < EMB * EMB; i += 256) {
    sWq[i >> 5][i & 31] = Wq[i];
    sWo[i >> 5][i & 31] = Wo[i];
  }
  if (t < EMB) { sbq[t] = bq[t]; sbo[t] = bo[t]; }
  {
    int r = t >> 5, c = t & 31;
    sX[r][c] = query[((size_t)n * SEQ + qrow0 + r) * EMB + c];
    sX[r + 8][c] = query[((size_t)n * SEQ + qrow0 + r + 8) * EMB + c];
  }
  __syncthreads();

  // q projection for 4 rows x this head's 4 dims, scaled by (1/sqrt(32))*log2(e)
  const float SC = 0.17677669529663687f * 1.4426950408889634f;
  float q[4][4];
#pragma unroll
  for (int r = 0; r < 4; ++r)
#pragma unroll
    for (int d = 0; d < 4; ++d) q[r][d] = sbq[4 * h + d];
#pragma unroll
  for (int j = 0; j < EMB; ++j) {
    float w0 = sWq[j][4 * h + 0], w1 = sWq[j][4 * h + 1];
    float w2 = sWq[j][4 * h + 2], w3 = sWq[j][4 * h + 3];
#pragma unroll
    for (int r = 0; r < 4; ++r) {
      float x = sX[4 * rl + r][j];
      q[r][0] = fmaf(x, w0, q[r][0]);
      q[r][1] = fmaf(x, w1, q[r][1]);
      q[r][2] = fmaf(x, w2, q[r][2]);
      q[r][3] = fmaf(x, w3, q[r][3]);
    }
  }
  v2f q2[2][4];
#pragma unroll
  for (int p = 0; p < 2; ++p)
#pragma unroll
    for (int d = 0; d < 4; ++d) {
      q2[p][d].x = q[2 * p][d] * SC;
      q2[p][d].y = q[2 * p + 1][d] * SC;
    }

  const float* kptr = Kp + (size_t)n * SEQ * EMB + (size_t)ks4 * EMB + 4 * h;
  const float* vptr = Vp + (size_t)n * SEQ * EMB + (size_t)ks4 * EMB + 4 * h;
  size_t rb = (size_t)n * SEQ + qrow0 + 4 * rl;
  const uint* mwp = pmw + rb * (SEQ / 32);

  v2f l2[2], ac2[2][4];
#pragma unroll
  for (int p = 0; p < 2; ++p) {
    l2[p] = splat2(0.0f);
#pragma unroll
    for (int d = 0; d < 4; ++d) ac2[p][d] = splat2(0.0f);
  }

  float4 ka[4], va[4]; uint4 ma;
  float4 kb[4], vb[4]; uint4 mb;
  load_tile(kptr, vptr, mwp, ka, va, ma);
  for (int i = 0; i < 31; ++i) {
    load_tile(kptr, vptr, mwp, kb, vb, mb);
    compute_tile(ka, va, ma, ks4, q2, l2, ac2);
    load_tile(kptr, vptr, mwp, ka, va, ma);
    compute_tile(kb, vb, mb, ks4, q2, l2, ac2);
  }
  load_tile(kptr, vptr, mwp, kb, vb, mb);
  compute_tile(ka, va, ma, ks4, q2, l2, ac2);
  compute_tile(kb, vb, mb, ks4, q2, l2, ac2);

  // merge the 8 k-split partials: plain sums (butterfly over lane bits 3-5)
#pragma unroll
  for (int d = 8; d <= 32; d <<= 1) {
#pragma unroll
    for (int p = 0; p < 2; ++p) {
      l2[p].x += __shfl_xor(l2[p].x, d);
      l2[p].y += __shfl_xor(l2[p].y, d);
#pragma unroll
      for (int e = 0; e < 4; ++e) {
        ac2[p][e].x += __shfl_xor(ac2[p][e].x, d);
        ac2[p][e].y += __shfl_xor(ac2[p][e].y, d);
      }
    }
  }

  if (ks < 4) {
#pragma unroll
    for (int p = 0; p < 2; ++p) {
      float invA = __builtin_amdgcn_rcpf(l2[p].x);
      float invB = __builtin_amdgcn_rcpf(l2[p].y);
      float vA = (ks == 0) ? ac2[p][0].x : (ks == 1) ? ac2[p][1].x
               : (ks == 2) ? ac2[p][2].x : ac2[p][3].x;
      float vB = (ks == 0) ? ac2[p][0].y : (ks == 1) ? ac2[p][1].y
               : (ks == 2) ? ac2[p][2].y : ac2[p][3].y;
      sCtx[4 * rl + 2 * p + 0][4 * h + ks] = vA * invA;
      sCtx[4 * rl + 2 * p + 1][4 * h + ks] = vB * invB;
    }
  }
  __syncthreads();

  // output projection
  int e = t & 31;
#pragma unroll
  for (int rr = 0; rr < 2; ++rr) {
    int r = (t >> 5) + 8 * rr;
    float o = sbo[e];
#pragma unroll
    for (int j = 0; j < EMB; ++j) o = fmaf(sCtx[r][j], sWo[j][e], o);
    out[((size_t)n * SEQ + qrow0 + r) * EMB + e] = o;
  }
}

extern "C" void kernel_launch(void* const* d_in, const int* in_sizes, int n_in,
                              void* d_out, int out_size, void* d_ws, size_t ws_size,
                              hipStream_t stream) {
  const float* query = (const float*)d_in[0];
  const float* key   = (const float*)d_in[1];
  const float* value = (const float*)d_in[2];
  const int*   mask  = (const int*)d_in[3];
  const float* Wq = (const float*)d_in[4];
  const float* bq = (const float*)d_in[5];
  const float* Wk = (const float*)d_in[6];
  const float* bk = (const float*)d_in[7];
  const float* Wv = (const float*)d_in[8];
  const float* bv = (const float*)d_in[9];
  const float* Wo = (const float*)d_in[10];
  const float* bo = (const float*)d_in[11];
  float* out = (float*)d_out;

  float* Kp = (float*)d_ws;                       // 1 MB
  float* Vp = Kp + (size_t)NB * SEQ * EMB;        // 1 MB
  uint* pmw = (uint*)(Vp + (size_t)NB * SEQ * EMB);  // 2 MB packed mask bits

  mask_pack_kernel<<<dim3(NB * SEQ * SEQ / 4 / 256), dim3(256), 0, stream>>>(
      mask, pmw);
  proj_kv_kernel<<<dim3(2 * NB * SEQ / 8), dim3(256), 0, stream>>>(
      key, value, Wk, bk, Wv, bv, Kp, Vp);
  attn_kernel<<<dim3(NB * (SEQ / 16)), dim3(256), 0, stream>>>(
      query, pmw, Kp, Vp, Wq, bq, Wo, bo, out);
}